// Round 2
// baseline (253.540 us; speedup 1.0000x reference)
//
#include <hip/hip_runtime.h>
#include <stdint.h>
#include <math.h>

// Problem constants
#define BROWS 8192
#define SDIM  512
#define HDIM  512
#define NCOL  8704          // S*(2K+1)
#define EPSK  1e-6f
#define LOG2E  1.442695041f
#define TWOL2E 2.885390082f
#define LN2    0.6931471806f

typedef __attribute__((ext_vector_type(8))) short bf16x8;   // MFMA A/B frag (4 VGPR)
typedef __attribute__((ext_vector_type(4))) short bf16x4;
typedef __attribute__((ext_vector_type(4))) float f32x4;    // MFMA C/D frag

__device__ __forceinline__ unsigned short f2bf(float f) {   // RTNE f32->bf16
    unsigned u = __float_as_uint(f);
    u += 0x7fffu + ((u >> 16) & 1u);
    return (unsigned short)(u >> 16);
}
__device__ __forceinline__ unsigned short f2bf_fast(float f) { // round-half-up (2 inst)
    return (unsigned short)((__float_as_uint(f) + 0x8000u) >> 16);
}
__device__ __forceinline__ float bf2f(unsigned short s) {
    return __uint_as_float(((unsigned)s) << 16);
}
#define EXP2F(x) __builtin_amdgcn_exp2f(x)   // v_exp_f32 (base 2)
#define LOG2F(x) __builtin_amdgcn_logf(x)    // v_log_f32 (base 2)
#define RCPF(x)  __builtin_amdgcn_rcpf(x)

// fast tanh, clamp-free: |2*log2e*x| < ~60 << 128 (bounded by sum|W|)
__device__ __forceinline__ float ftanh(float x) {
    float e = EXP2F(TWOL2E * x);
    return (e - 1.f) * RCPF(e + 1.f);
}
// log2e * tanh(acc + bias), bias pre-scaled by 2*log2e
__device__ __forceinline__ float ftanh_l2e(float acc, float bias2L) {
    float e = EXP2F(fmaf(acc, TWOL2E, bias2L));
    return fmaf(e, LOG2E, -LOG2E) * RCPF(e + 1.f);
}

// async global->LDS, 16B per lane; LDS dst is wave-uniform base + lane*16
#define GLD16(g, l)                                                         \
    __builtin_amdgcn_global_load_lds(                                       \
        (const __attribute__((address_space(1))) void*)(g),                 \
        (__attribute__((address_space(3))) void*)(l), 16, 0, 0)

// counted waits + compiler fences (T4 discipline; asm "memory" pins IR loads)
#define WAITV(N) asm volatile("s_waitcnt vmcnt(" #N ")" ::: "memory")
#define WAITL0   asm volatile("s_waitcnt lgkmcnt(0)" ::: "memory")
#define CFENCE   asm volatile("" ::: "memory")

// ---------------------------------------------------------------------------
// PREP (one kernel, 2720 blocks) — restructured for TLP (short latency chains):
//  [0,2176)    : pack W2 -> W2p image [colblk(32)][kk(16)][chunk(17)][r16][e32]
//  [2176,2432) : transpose W1 -> W1T bf16 (k-contiguous)
//  [2432,2688) : x_a -> out[:, :512] copy
//  [2688,2720) : out tail init: out[B*1024 + b] = logd[b]
// ---------------------------------------------------------------------------
__global__ __launch_bounds__(256) void prep_k(
    const float* __restrict__ W2, unsigned short* __restrict__ W2p,
    const float* __restrict__ W1, unsigned short* __restrict__ W1T,
    const float* __restrict__ logd, float* __restrict__ out,
    const float* __restrict__ x)
{
    __shared__ float tile[32 * 33];
    const int t   = threadIdx.x;
    const int bid = blockIdx.x;
    if (bid < 2176) {
        const int ct = bid >> 2;              // 0..543
        const int kq = bid & 3;               // kk quarter
        const int colbase = ct * 16;
        const int colblk = ct / 17;
        const int chunk  = ct - colblk * 17;
        const int k32 = t >> 3;               // 0..31
        const int c2  = (t & 7) * 2;          // 0..14
        const int r   = t >> 4;               // 0..15
        const int e2  = (t & 15) * 2;         // 0..30
        for (int kk = kq * 4; kk < kq * 4 + 4; ++kk) {
            float2 v = *(const float2*)&W2[(size_t)(kk * 32 + k32) * NCOL + colbase + c2];
            __syncthreads();
            tile[k32 * 17 + c2 + 0] = v.x;
            tile[k32 * 17 + c2 + 1] = v.y;
            __syncthreads();
            const size_t off = (((size_t)colblk * 16 + kk) * 17 + chunk) * 512;
            ushort2 o;
            o.x = f2bf(tile[(e2 + 0) * 17 + r]);
            o.y = f2bf(tile[(e2 + 1) * 17 + r]);
            *(ushort2*)&W2p[off + (size_t)r * 32 + e2] = o;
        }
    } else if (bid < 2432) {
        const int bt = bid - 2176;            // 0..255
        const int cb = (bt & 15) * 32;
        const int rb = (bt >> 4) * 32;
        const int ty = t >> 3, tx = (t & 7) * 4;
        float4 v = *(const float4*)&W1[(size_t)(rb + ty) * HDIM + cb + tx];
        tile[ty * 33 + tx + 0] = v.x;
        tile[ty * 33 + tx + 1] = v.y;
        tile[ty * 33 + tx + 2] = v.z;
        tile[ty * 33 + tx + 3] = v.w;
        __syncthreads();
        const int oy = t >> 3, ox = (t & 7) * 4;
        bf16x4 o;
        o[0] = (short)f2bf(tile[(ox + 0) * 33 + oy]);
        o[1] = (short)f2bf(tile[(ox + 1) * 33 + oy]);
        o[2] = (short)f2bf(tile[(ox + 2) * 33 + oy]);
        o[3] = (short)f2bf(tile[(ox + 3) * 33 + oy]);
        *(bf16x4*)&W1T[(size_t)(cb + oy) * SDIM + rb + ox] = o;
    } else if (bid < 2688) {
        // x_a -> out[:, :512] copy: 8192 rows x 128 float4
        const int bt = bid - 2432;            // 0..255
        const float4* xi = (const float4*)x;
        float4* oo = (float4*)out;
        const int base = bt * 4096 + t;
#pragma unroll
        for (int k2 = 0; k2 < 16; ++k2) {
            const int f = base + k2 * 256;
            const int row = f >> 7, c4 = f & 127;
            oo[(size_t)row * 256 + c4] = xi[(size_t)row * 256 + c4];
        }
    } else {
        const int b = (bid - 2688) * 256 + t;   // 0..8191
        out[(size_t)BROWS * (2 * SDIM) + b] = logd[b];
    }
}

// ---------------------------------------------------------------------------
// GEMM1 (MFMA): hid = bf16(tanh((x_a-0.5) @ W1 + b1)).
// gemm2-style loop: GLD16 staging (A raw f32, converted at read), dbuf,
// one barrier/K-step, issue one step ahead. XOR swizzle both operands.
// ---------------------------------------------------------------------------
__global__ __launch_bounds__(256) void gemm1_mfma(
    const float* __restrict__ x,
    const unsigned short* __restrict__ W1T,   // (H,S) bf16 k-contiguous
    const float* __restrict__ b1,
    unsigned short* __restrict__ hid)         // (B,H) bf16
{
    __shared__ float Asf[2][64 * 32];         // 2 x 8KB raw f32 x-tile
    __shared__ short Bsb[2][128 * 32];        // 2 x 8KB bf16 W1T-tile

    const int flat = blockIdx.y * 4 + blockIdx.x;      // 0..511
    const int xcd  = flat & 7;
    const int j8   = flat >> 3;                        // 0..63
    const int bn   = (j8 & 3) * 128;
    const int bm   = (xcd * 16 + (j8 >> 2)) * 64;

    const int tid  = threadIdx.x;
    const int lane = tid & 63;
    const int wave = tid >> 6;
    const int ln15 = lane & 15;
    const int quad = lane >> 4;
    const int wm   = (wave >> 1) * 32;
    const int wn   = (wave & 1) * 64;
    const int brow = lane >> 2;
    const int bsub_sw = (lane & 3) ^ ((lane >> 3) & 3);    // bf16 chunk src swizzle
    const int arow8   = lane >> 3;                          // f32 chunk: 8 rows/1KB
    const int aslot_sw = (lane & 7) ^ (arow8 & 7);          // f32 chunk src swizzle
    const int qsw = (quad ^ ((ln15 >> 1) & 3)) * 8;         // bf16 read swizzle
    const int ag  = ln15 & 7;                               // f32 read swizzle

    f32x4 acc[2][4];
#pragma unroll
    for (int i = 0; i < 2; i++)
#pragma unroll
        for (int j = 0; j < 4; j++) acc[i][j] = (f32x4){0.f, 0.f, 0.f, 0.f};

    const float* asrc = &x[(size_t)(bm + arow8) * (2 * SDIM) + aslot_sw * 4];
    const unsigned short* bsrc = &W1T[(size_t)(bn + brow) * SDIM + bsub_sw * 8];

    auto issue = [&](int n, int p) {
#pragma unroll
        for (int c = 0; c < 2; ++c) {             // A: 8 chunks of 8 rows x 32 f32
            const int ca = wave * 2 + c;
            GLD16(asrc + (size_t)ca * 8 * (2 * SDIM) + n * 32, &Asf[p][ca * 256]);
        }
#pragma unroll
        for (int c = 0; c < 2; ++c) {             // B: 8 chunks of 16 rows x 32 bf16
            const int cb = wave * 2 + c;
            GLD16(bsrc + (size_t)cb * 16 * SDIM + n * 32, &Bsb[p][cb * 512]);
        }
    };

    issue(0, 0);                                  // prologue
    for (int n = 0; n < 16; ++n) {
        __syncthreads();                          // drains loads(n) + prior reads
        if (n < 15) issue(n + 1, (n + 1) & 1);
        const float* As = Asf[n & 1];
        const short* Bs = Bsb[n & 1];

        bf16x8 af[2], bfr[4];
#pragma unroll
        for (int i = 0; i < 2; ++i) {
            const int r = wm + i * 16 + ln15;
            f32x4 a0 = *(const f32x4*)&As[r * 32 + ((2 * quad + 0) ^ ag) * 4];
            f32x4 a1 = *(const f32x4*)&As[r * 32 + ((2 * quad + 1) ^ ag) * 4];
            bf16x8 v;
            v[0] = (short)f2bf_fast(a0[0] - 0.5f); v[1] = (short)f2bf_fast(a0[1] - 0.5f);
            v[2] = (short)f2bf_fast(a0[2] - 0.5f); v[3] = (short)f2bf_fast(a0[3] - 0.5f);
            v[4] = (short)f2bf_fast(a1[0] - 0.5f); v[5] = (short)f2bf_fast(a1[1] - 0.5f);
            v[6] = (short)f2bf_fast(a1[2] - 0.5f); v[7] = (short)f2bf_fast(a1[3] - 0.5f);
            af[i] = v;
        }
#pragma unroll
        for (int j = 0; j < 4; ++j)
            bfr[j] = *(const bf16x8*)&Bs[(wn + j * 16 + ln15) * 32 + qsw];
#pragma unroll
        for (int i = 0; i < 2; ++i)
#pragma unroll
            for (int j = 0; j < 4; ++j)
                acc[i][j] = __builtin_amdgcn_mfma_f32_16x16x32_bf16(af[i], bfr[j], acc[i][j], 0, 0, 0);
    }

#pragma unroll
    for (int j = 0; j < 4; j++) {
        const int col = bn + wn + j * 16 + ln15;
        const float bias = b1[col];
#pragma unroll
        for (int i = 0; i < 2; i++) {
#pragma unroll
            for (int r = 0; r < 4; r++) {
                const int row = bm + wm + i * 16 + quad * 4 + r;
                hid[(size_t)row * HDIM + col] = f2bf(ftanh(acc[i][j][r] + bias));
            }
        }
    }
}

// ---------------------------------------------------------------------------
// GEMM2 (MFMA) fused with spline epilogue. BM=64 x BN=272 (16 splines).
// Grid (128 row-stripes, 32 colblks), x fastest (W2p slice L2-resident).
//
// NEW (T3/T4/T5): depth-2 pipeline with THREE LDS buffers, counted vmcnt
// (never drains in-loop: per-wave in-flight = loads(n)+loads(n+1), wait to
// 5 [waves 0-2] / 6 [wave 3] = exactly loads(n+1)), raw s_barrier (no
// compiler vmcnt(0) drain), issue(n+2) BEFORE the step's ds_reads/MFMA so
// every load has ~2 compute phases to land. setprio(1) around the MFMA
// cluster (waves now have role diversity -> T5 applies). Overwrite safety:
// WAITL0 before each barrier drains every wave's prior-step ds_reads, and
// issue(n+2) targets the buffer read at step n-1. LDS 64.5KB -> 2 blocks/CU
// (the 2-waves/SIMD regime where the m201 template reaches 62% MfmaUtil).
// Numerics bit-identical to round 1.
// ---------------------------------------------------------------------------
__global__ __launch_bounds__(256, 2) void gemm2_spline_mfma(
    const unsigned short* __restrict__ hid,   // (B,H) bf16
    const unsigned short* __restrict__ W2p,   // packed, see prep_k
    const float* __restrict__ b2,
    const float* __restrict__ x,              // x_b = cols [512,1024)
    float* __restrict__ out)                  // [B*1024 phi | B tail]
{
    __shared__ short smem[3 * 10752];         // 64512 B; 3-deep staging / netS union

    const int bm     = blockIdx.x * 64;       // x = row stripe (fastest)
    const int colblk = blockIdx.y;            // y = colblock
    const int tid  = threadIdx.x;
    const int lane = tid & 63;
    const int wave = tid >> 6;
    const int ln15 = lane & 15;
    const int quad = lane >> 4;
    const int brow = lane >> 2;
    const int bsub_sw = (lane & 3) ^ ((lane >> 3) & 3);    // staging src swizzle
    const int qsw = (quad ^ ((ln15 >> 1) & 3)) * 8;        // fragment read swizzle
    const int jstart = wave * 4;
    const int jcount = (wave == 3) ? 5 : 4;
    const int bcol = colblk * 272;

    f32x4 acc[4][5];
#pragma unroll
    for (int i = 0; i < 4; i++)
#pragma unroll
        for (int j = 0; j < 5; j++) acc[i][j] = (f32x4){0.f, 0.f, 0.f, 0.f};

    const unsigned short* bbase =
        W2p + ((size_t)colblk * 16) * 17 * 512 + (size_t)(lane >> 2) * 32 + (size_t)bsub_sw * 8;
    const unsigned short* abase =
        &hid[(size_t)(bm + wave * 16 + brow) * HDIM + bsub_sw * 8];

    // issue staging loads for K-step n into buffer p (per wave: 1 A + jcount B)
    auto issue = [&](int n, int p) {
        short* dst = smem + p * 10752;
        GLD16(abase + n * 32, &dst[wave * 512]);
        const unsigned short* bk = bbase + (size_t)n * (17 * 512);
        for (int c = 0; c < jcount; ++c) {
            const int chunk = jstart + c;
            GLD16(bk + (size_t)chunk * 512, &dst[2048 + chunk * 512]);
        }
    };

    issue(0, 0);                               // prologue: depth-2 prefetch
    issue(1, 1);
    int cur = 0, stg = 2;                      // read buffer / stage target
    for (int n = 0; n < 16; ++n) {
        // wait own loads(n) done; leave loads(n+1) in flight (counted vmcnt)
        if (n < 15) { if (wave == 3) { WAITV(6); } else { WAITV(5); } }
        else        { WAITV(0); }
        WAITL0;                                // own prior-step ds_reads drained
        __builtin_amdgcn_s_barrier();          // all waves' loads(n) visible
        CFENCE;                                // pin following mem ops below bar
        if (n + 2 < 16) issue(n + 2, stg);     // early issue -> 2 phases to land

        const short* As = smem + cur * 10752;
        const short* Bs = As + 2048;
        bf16x8 af[4];
#pragma unroll
        for (int i = 0; i < 4; i++)
            af[i] = *(const bf16x8*)&As[(i * 16 + ln15) * 32 + qsw];

        __builtin_amdgcn_s_setprio(1);
#define KSTEP(JC)                                                               \
        _Pragma("unroll") for (int j = 0; j < (JC); ++j) {                      \
            bf16x8 bfr = *(const bf16x8*)&Bs[((jstart + j) * 16 + ln15) * 32 + qsw]; \
            _Pragma("unroll") for (int i = 0; i < 4; ++i)                       \
                acc[i][j] = __builtin_amdgcn_mfma_f32_16x16x32_bf16(af[i], bfr, acc[i][j], 0, 0, 0); \
        }
        if (wave == 3) { KSTEP(5) } else { KSTEP(4) }
#undef KSTEP
        __builtin_amdgcn_s_setprio(0);

        cur = (cur == 2) ? 0 : cur + 1;
        stg = (stg == 2) ? 0 : stg + 1;
    }

    // prefetch x_b for phase 2 (latency hidden under phase-1 tanh work)
    const int sp = tid & 15;
    const int r0 = tid >> 4;
    const int sglob = colblk * 16 + sp;
    float xbv[4];
#pragma unroll
    for (int t = 0; t < 4; ++t)
        xbv[t] = x[(size_t)(bm + t * 16 + r0) * (2 * SDIM) + SDIM + sglob];

    // ---- phase 1: s = log2e*tanh(acc+bias) -> netS [col][row], stride 68 ----
    __syncthreads();
#define EPI1(JC)                                                                \
    _Pragma("unroll") for (int j = 0; j < (JC); ++j) {                          \
        const int col_l = (jstart + j) * 16 + ln15;                             \
        const float bias2L = b2[bcol + col_l] * TWOL2E;                         \
        _Pragma("unroll") for (int i = 0; i < 4; ++i) {                         \
            bf16x4 o;                                                           \
            _Pragma("unroll") for (int r = 0; r < 4; ++r)                       \
                o[r] = (short)f2bf_fast(ftanh_l2e(acc[i][j][r], bias2L));       \
            *(bf16x4*)&smem[col_l * 68 + i * 16 + quad * 4] = o;                \
        }                                                                       \
    }
    if (wave == 3) { EPI1(5) } else { EPI1(4) }
#undef EPI1
    __syncthreads();

    // ---- phase 2: spline math per (row, spline), unnormalized formulation ----
    for (int t = 0; t < 4; ++t) {
        const int row_l = t * 16 + r0;
        const int row = bm + row_l;
        const int cbase = sp * 17 * 68 + row_l;     // netS [col][row]

        float s[17];
#pragma unroll
        for (int c = 0; c < 17; c++)
            s[c] = bf2f((unsigned short)smem[cbase + c * 68]);

        // eh = 2^s (h part), e = 2^s (w part); |s|<1.45 so no max-subtraction
        float eh[9], e[8];
#pragma unroll
        for (int j = 0; j < 9; j++) eh[j] = EXP2F(s[j]);
#pragma unroll
        for (int c = 0; c < 8; c++) e[c]  = EXP2F(s[9 + c]);

        float cum_e[8], cum_u[8];
        cum_e[0] = e[0];
        cum_u[0] = e[0] * (eh[0] + eh[1]);
#pragma unroll
        for (int c = 1; c < 8; c++) {
            cum_e[c] = cum_e[c - 1] + e[c];
            cum_u[c] = fmaf(e[c], eh[c] + eh[c + 1], cum_u[c - 1]);
        }
        const float se = cum_e[7];
        const float su = cum_u[7];
        const float thr = xbv[t] * se;      // compare vs unnormalized knots

        float selE = e[0], selEH = eh[0], selEH1 = eh[1];
        float selCE = -EPSK * se, selCU = 0.f;
#pragma unroll
        for (int c = 1; c < 8; c++) {
            const bool tt = (cum_e[c - 1] < thr);
            selE   = tt ? e[c]         : selE;
            selEH  = tt ? eh[c]        : selEH;
            selEH1 = tt ? eh[c + 1]    : selEH1;
            selCE  = tt ? cum_e[c - 1] : selCE;
            selCU  = tt ? cum_u[c - 1] : selCU;
        }

        const float alpha = (thr - selCE) * RCPF(selE);
        const float dlt   = selEH1 - selEH;
        const float su_inv = RCPF(su);
        float p = fmaf(2.f * alpha, selE * selEH, selCU);
        p = fmaf(alpha * alpha, selE * dlt, p);
        out[(size_t)row * (2 * SDIM) + SDIM + sglob] = p * su_inv;

        const float g = fmaf(alpha, dlt, selEH) * (2.f * se * su_inv);
        float lg = LOG2F(g);
        lg += __shfl_xor(lg, 1);
        lg += __shfl_xor(lg, 2);
        lg += __shfl_xor(lg, 4);
        lg += __shfl_xor(lg, 8);
        if (sp == 0)
            atomicAdd(&out[(size_t)BROWS * (2 * SDIM) + row], -lg * LN2);
    }
}

// ---------------------------------------------------------------------------
extern "C" void kernel_launch(void* const* d_in, const int* in_sizes, int n_in,
                              void* d_out, int out_size, void* d_ws, size_t ws_size,
                              hipStream_t stream) {
    const float* x    = (const float*)d_in[0];
    const float* logd = (const float*)d_in[1];
    const float* W1   = (const float*)d_in[2];
    const float* b1   = (const float*)d_in[3];
    const float* W2   = (const float*)d_in[4];
    const float* b2   = (const float*)d_in[5];
    float* out = (float*)d_out;

    // ws layout (~17.9 MiB, unchanged)
    char* ws = (char*)d_ws;
    unsigned short* W1T = (unsigned short*)(ws + 32768);     // 512x512 bf16
    unsigned short* W2p = (unsigned short*)(ws + 557056);    // 8704x512 bf16 packed
    unsigned short* hid = (unsigned short*)(ws + 9469952);   // 8192x512 bf16

    prep_k<<<2720, 256, 0, stream>>>(W2, W2p, W1, W1T, logd, out, x);
    gemm1_mfma<<<dim3(4, 128), 256, 0, stream>>>(x, W1T, b1, hid);
    gemm2_spline_mfma<<<dim3(128, 32), 256, 0, stream>>>(hid, W2p, b2, x, out);
}

// Round 4
// 221.231 us; speedup vs baseline: 1.1460x; 1.1460x over previous
//
#include <hip/hip_runtime.h>
#include <stdint.h>
#include <math.h>

// Problem constants
#define BROWS 8192
#define SDIM  512
#define HDIM  512
#define NCOL  8704          // S*(2K+1)
#define EPSK  1e-6f
#define LOG2E  1.442695041f
#define TWOL2E 2.885390082f
#define LN2    0.6931471806f

typedef __attribute__((ext_vector_type(8))) short bf16x8;   // MFMA A/B frag (4 VGPR)
typedef __attribute__((ext_vector_type(4))) short bf16x4;
typedef __attribute__((ext_vector_type(4))) float f32x4;    // MFMA C/D frag

__device__ __forceinline__ unsigned short f2bf(float f) {   // RTNE f32->bf16
    unsigned u = __float_as_uint(f);
    u += 0x7fffu + ((u >> 16) & 1u);
    return (unsigned short)(u >> 16);
}
__device__ __forceinline__ unsigned short f2bf_fast(float f) { // round-half-up (2 inst)
    return (unsigned short)((__float_as_uint(f) + 0x8000u) >> 16);
}
__device__ __forceinline__ float bf2f(unsigned short s) {
    return __uint_as_float(((unsigned)s) << 16);
}
#define EXP2F(x) __builtin_amdgcn_exp2f(x)   // v_exp_f32 (base 2)
#define LOG2F(x) __builtin_amdgcn_logf(x)    // v_log_f32 (base 2)
#define RCPF(x)  __builtin_amdgcn_rcpf(x)

// fast tanh, clamp-free: |2*log2e*x| < ~60 << 128 (bounded by sum|W|)
__device__ __forceinline__ float ftanh(float x) {
    float e = EXP2F(TWOL2E * x);
    return (e - 1.f) * RCPF(e + 1.f);
}
// log2e * tanh(acc + bias), bias pre-scaled by 2*log2e
__device__ __forceinline__ float ftanh_l2e(float acc, float bias2L) {
    float e = EXP2F(fmaf(acc, TWOL2E, bias2L));
    return fmaf(e, LOG2E, -LOG2E) * RCPF(e + 1.f);
}

// async global->LDS, 16B per lane; LDS dst is wave-uniform base + lane*16
#define GLD16(g, l)                                                         \
    __builtin_amdgcn_global_load_lds(                                       \
        (const __attribute__((address_space(1))) void*)(g),                 \
        (__attribute__((address_space(3))) void*)(l), 16, 0, 0)

// ---------------------------------------------------------------------------
// PREP (one kernel, 2720 blocks) — restructured for TLP (short latency chains):
//  [0,2176)    : pack W2 -> W2p image [colblk(32)][kk(16)][chunk(17)][r16][e32]
//  [2176,2432) : transpose W1 -> W1T bf16 (k-contiguous)
//  [2432,2688) : x_a -> out[:, :512] copy
//  [2688,2720) : out tail init: out[B*1024 + b] = logd[b]
// ---------------------------------------------------------------------------
__global__ __launch_bounds__(256) void prep_k(
    const float* __restrict__ W2, unsigned short* __restrict__ W2p,
    const float* __restrict__ W1, unsigned short* __restrict__ W1T,
    const float* __restrict__ logd, float* __restrict__ out,
    const float* __restrict__ x)
{
    __shared__ float tile[32 * 33];
    const int t   = threadIdx.x;
    const int bid = blockIdx.x;
    if (bid < 2176) {
        const int ct = bid >> 2;              // 0..543
        const int kq = bid & 3;               // kk quarter
        const int colbase = ct * 16;
        const int colblk = ct / 17;
        const int chunk  = ct - colblk * 17;
        const int k32 = t >> 3;               // 0..31
        const int c2  = (t & 7) * 2;          // 0..14
        const int r   = t >> 4;               // 0..15
        const int e2  = (t & 15) * 2;         // 0..30
        for (int kk = kq * 4; kk < kq * 4 + 4; ++kk) {
            float2 v = *(const float2*)&W2[(size_t)(kk * 32 + k32) * NCOL + colbase + c2];
            __syncthreads();
            tile[k32 * 17 + c2 + 0] = v.x;
            tile[k32 * 17 + c2 + 1] = v.y;
            __syncthreads();
            const size_t off = (((size_t)colblk * 16 + kk) * 17 + chunk) * 512;
            ushort2 o;
            o.x = f2bf(tile[(e2 + 0) * 17 + r]);
            o.y = f2bf(tile[(e2 + 1) * 17 + r]);
            *(ushort2*)&W2p[off + (size_t)r * 32 + e2] = o;
        }
    } else if (bid < 2432) {
        const int bt = bid - 2176;            // 0..255
        const int cb = (bt & 15) * 32;
        const int rb = (bt >> 4) * 32;
        const int ty = t >> 3, tx = (t & 7) * 4;
        float4 v = *(const float4*)&W1[(size_t)(rb + ty) * HDIM + cb + tx];
        tile[ty * 33 + tx + 0] = v.x;
        tile[ty * 33 + tx + 1] = v.y;
        tile[ty * 33 + tx + 2] = v.z;
        tile[ty * 33 + tx + 3] = v.w;
        __syncthreads();
        const int oy = t >> 3, ox = (t & 7) * 4;
        bf16x4 o;
        o[0] = (short)f2bf(tile[(ox + 0) * 33 + oy]);
        o[1] = (short)f2bf(tile[(ox + 1) * 33 + oy]);
        o[2] = (short)f2bf(tile[(ox + 2) * 33 + oy]);
        o[3] = (short)f2bf(tile[(ox + 3) * 33 + oy]);
        *(bf16x4*)&W1T[(size_t)(cb + oy) * SDIM + rb + ox] = o;
    } else if (bid < 2688) {
        // x_a -> out[:, :512] copy: 8192 rows x 128 float4
        const int bt = bid - 2432;            // 0..255
        const float4* xi = (const float4*)x;
        float4* oo = (float4*)out;
        const int base = bt * 4096 + t;
#pragma unroll
        for (int k2 = 0; k2 < 16; ++k2) {
            const int f = base + k2 * 256;
            const int row = f >> 7, c4 = f & 127;
            oo[(size_t)row * 256 + c4] = xi[(size_t)row * 256 + c4];
        }
    } else {
        const int b = (bid - 2688) * 256 + t;   // 0..8191
        out[(size_t)BROWS * (2 * SDIM) + b] = logd[b];
    }
}

// ---------------------------------------------------------------------------
// GEMM1 (MFMA): hid = bf16(tanh((x_a-0.5) @ W1 + b1)).
// gemm2-style loop: GLD16 staging (A raw f32, converted at read), dbuf,
// one barrier/K-step, issue one step ahead. XOR swizzle both operands.
// ---------------------------------------------------------------------------
__global__ __launch_bounds__(256) void gemm1_mfma(
    const float* __restrict__ x,
    const unsigned short* __restrict__ W1T,   // (H,S) bf16 k-contiguous
    const float* __restrict__ b1,
    unsigned short* __restrict__ hid)         // (B,H) bf16
{
    __shared__ float Asf[2][64 * 32];         // 2 x 8KB raw f32 x-tile
    __shared__ short Bsb[2][128 * 32];        // 2 x 8KB bf16 W1T-tile

    const int flat = blockIdx.y * 4 + blockIdx.x;      // 0..511
    const int xcd  = flat & 7;
    const int j8   = flat >> 3;                        // 0..63
    const int bn   = (j8 & 3) * 128;
    const int bm   = (xcd * 16 + (j8 >> 2)) * 64;

    const int tid  = threadIdx.x;
    const int lane = tid & 63;
    const int wave = tid >> 6;
    const int ln15 = lane & 15;
    const int quad = lane >> 4;
    const int wm   = (wave >> 1) * 32;
    const int wn   = (wave & 1) * 64;
    const int brow = lane >> 2;
    const int bsub_sw = (lane & 3) ^ ((lane >> 3) & 3);    // bf16 chunk src swizzle
    const int arow8   = lane >> 3;                          // f32 chunk: 8 rows/1KB
    const int aslot_sw = (lane & 7) ^ (arow8 & 7);          // f32 chunk src swizzle
    const int qsw = (quad ^ ((ln15 >> 1) & 3)) * 8;         // bf16 read swizzle
    const int ag  = ln15 & 7;                               // f32 read swizzle

    f32x4 acc[2][4];
#pragma unroll
    for (int i = 0; i < 2; i++)
#pragma unroll
        for (int j = 0; j < 4; j++) acc[i][j] = (f32x4){0.f, 0.f, 0.f, 0.f};

    const float* asrc = &x[(size_t)(bm + arow8) * (2 * SDIM) + aslot_sw * 4];
    const unsigned short* bsrc = &W1T[(size_t)(bn + brow) * SDIM + bsub_sw * 8];

    auto issue = [&](int n, int p) {
#pragma unroll
        for (int c = 0; c < 2; ++c) {             // A: 8 chunks of 8 rows x 32 f32
            const int ca = wave * 2 + c;
            GLD16(asrc + (size_t)ca * 8 * (2 * SDIM) + n * 32, &Asf[p][ca * 256]);
        }
#pragma unroll
        for (int c = 0; c < 2; ++c) {             // B: 8 chunks of 16 rows x 32 bf16
            const int cb = wave * 2 + c;
            GLD16(bsrc + (size_t)cb * 16 * SDIM + n * 32, &Bsb[p][cb * 512]);
        }
    };

    issue(0, 0);                                  // prologue
    for (int n = 0; n < 16; ++n) {
        __syncthreads();                          // drains loads(n) + prior reads
        if (n < 15) issue(n + 1, (n + 1) & 1);
        const float* As = Asf[n & 1];
        const short* Bs = Bsb[n & 1];

        bf16x8 af[2], bfr[4];
#pragma unroll
        for (int i = 0; i < 2; ++i) {
            const int r = wm + i * 16 + ln15;
            f32x4 a0 = *(const f32x4*)&As[r * 32 + ((2 * quad + 0) ^ ag) * 4];
            f32x4 a1 = *(const f32x4*)&As[r * 32 + ((2 * quad + 1) ^ ag) * 4];
            bf16x8 v;
            v[0] = (short)f2bf_fast(a0[0] - 0.5f); v[1] = (short)f2bf_fast(a0[1] - 0.5f);
            v[2] = (short)f2bf_fast(a0[2] - 0.5f); v[3] = (short)f2bf_fast(a0[3] - 0.5f);
            v[4] = (short)f2bf_fast(a1[0] - 0.5f); v[5] = (short)f2bf_fast(a1[1] - 0.5f);
            v[6] = (short)f2bf_fast(a1[2] - 0.5f); v[7] = (short)f2bf_fast(a1[3] - 0.5f);
            af[i] = v;
        }
#pragma unroll
        for (int j = 0; j < 4; ++j)
            bfr[j] = *(const bf16x8*)&Bs[(wn + j * 16 + ln15) * 32 + qsw];
#pragma unroll
        for (int i = 0; i < 2; ++i)
#pragma unroll
            for (int j = 0; j < 4; ++j)
                acc[i][j] = __builtin_amdgcn_mfma_f32_16x16x32_bf16(af[i], bfr[j], acc[i][j], 0, 0, 0);
    }

#pragma unroll
    for (int j = 0; j < 4; j++) {
        const int col = bn + wn + j * 16 + ln15;
        const float bias = b1[col];
#pragma unroll
        for (int i = 0; i < 2; i++) {
#pragma unroll
            for (int r = 0; r < 4; r++) {
                const int row = bm + wm + i * 16 + quad * 4 + r;
                hid[(size_t)row * HDIM + col] = f2bf(ftanh(acc[i][j][r] + bias));
            }
        }
    }
}

// ---------------------------------------------------------------------------
// GEMM2 (MFMA) fused with spline epilogue.
// GEOMETRY: BM=128 x BN=272, 4 waves, each wave owns a 128x68 output tile
// (acc[8][4|5]). Rationale (round-1/2 post-mortem): the K-loop was LDS-read-
// throughput-bound (102 ds_read_b128/CU/step ~ 1220cy vs 1000cy step wall;
// MfmaUtil 27%, conflict-removal had zero effect). Doubling the per-wave M
// halves LDS bytes per FLOP (0.030 -> 0.022 B/FLOP): per-CU-step LDS ~800cy
// vs MFMA ~1100cy -> MFMA becomes the critical pipe. 2 blocks/CU (netS 71.8KB),
// acceptable because the kernel is throughput- not latency-bound.
// Loop structure = proven round-1 (simple dbuf, syncthreads, issue n+1 after
// barrier). Zero-conflict swizzle kept. Numerics bit-identical.
// ---------------------------------------------------------------------------
__global__ __launch_bounds__(256, 2) void gemm2_spline_mfma(
    const unsigned short* __restrict__ hid,   // (B,H) bf16
    const unsigned short* __restrict__ W2p,   // packed, see prep_k
    const float* __restrict__ b2,
    const float* __restrict__ x,              // x_b = cols [512,1024)
    float* __restrict__ out)                  // [B*1024 phi | B tail]
{
    // union: staging dbuf 2 x (A 4096 + B 8704) = 25600 shorts (51.2KB)
    //        netS [272 cols][132 rows] = 35904 shorts (71.8KB)  <- high water
    __shared__ short smem[35904];

    const int bm     = blockIdx.x * 128;      // x = row stripe (fastest)
    const int colblk = blockIdx.y;            // y = colblock
    const int tid  = threadIdx.x;
    const int lane = tid & 63;
    const int wave = tid >> 6;
    const int ln15 = lane & 15;
    const int quad = lane >> 4;
    const int brow = lane >> 2;
    const int bsub_sw = (lane & 3) ^ ((lane >> 3) & 3);    // staging src swizzle
    const int qsw = (quad ^ ((ln15 >> 1) & 3)) * 8;        // fragment read swizzle
    const int jstart = wave * 4;
    const int jcount = (wave == 3) ? 5 : 4;
    const int bcol = colblk * 272;

    f32x4 acc[8][5];
#pragma unroll
    for (int i = 0; i < 8; i++)
#pragma unroll
        for (int j = 0; j < 5; j++) acc[i][j] = (f32x4){0.f, 0.f, 0.f, 0.f};

    const unsigned short* bbase =
        W2p + ((size_t)colblk * 16) * 17 * 512 + (size_t)(lane >> 2) * 32 + (size_t)bsub_sw * 8;
    // A: 8 chunks of 16 rows x 32 k; wave stages chunks {2w, 2w+1}
    const unsigned short* abase0 =
        &hid[(size_t)(bm + wave * 32 + brow) * HDIM + bsub_sw * 8];
    const unsigned short* abase1 = abase0 + 16 * HDIM;

    // issue staging loads for K-step n into buffer parity p (per wave: 2A + 4|5 B)
    auto issue = [&](int n, int p) {
        short* dst = smem + p * 12800;
        GLD16(abase0 + n * 32, &dst[(2 * wave + 0) * 512]);
        GLD16(abase1 + n * 32, &dst[(2 * wave + 1) * 512]);
        const unsigned short* bk = bbase + (size_t)n * (17 * 512);
        for (int c = 0; c < jcount; ++c) {
            const int chunk = jstart + c;
            GLD16(bk + (size_t)chunk * 512, &dst[4096 + chunk * 512]);
        }
    };

    issue(0, 0);                               // prologue
    for (int n = 0; n < 16; ++n) {
        __syncthreads();                       // drains loads(n) + prior reads
        if (n < 15) issue(n + 1, (n + 1) & 1);
        const short* As = smem + (n & 1) * 12800;
        const short* Bs = As + 4096;

        bf16x8 af[8];
#pragma unroll
        for (int i = 0; i < 8; i++)
            af[i] = *(const bf16x8*)&As[(i * 16 + ln15) * 32 + qsw];

#define KSTEP(JC)                                                               \
        _Pragma("unroll") for (int j = 0; j < (JC); ++j) {                      \
            bf16x8 bfr = *(const bf16x8*)&Bs[((jstart + j) * 16 + ln15) * 32 + qsw]; \
            _Pragma("unroll") for (int i = 0; i < 8; ++i)                       \
                acc[i][j] = __builtin_amdgcn_mfma_f32_16x16x32_bf16(af[i], bfr, acc[i][j], 0, 0, 0); \
        }
        if (wave == 3) { KSTEP(5) } else { KSTEP(4) }
#undef KSTEP
    }

    // prefetch x_b for phase 2 (latency hidden under phase-1 tanh work)
    const int sp = tid & 15;
    const int r0 = tid >> 4;
    const int sglob = colblk * 16 + sp;
    float xbv[8];
#pragma unroll
    for (int t = 0; t < 8; ++t)
        xbv[t] = x[(size_t)(bm + t * 16 + r0) * (2 * SDIM) + SDIM + sglob];

    // ---- phase 1: s = log2e*tanh(acc+bias) -> netS [col][row], stride 132 ----
    __syncthreads();
#define EPI1(JC)                                                                \
    _Pragma("unroll") for (int j = 0; j < (JC); ++j) {                          \
        const int col_l = (jstart + j) * 16 + ln15;                             \
        const float bias2L = b2[bcol + col_l] * TWOL2E;                         \
        _Pragma("unroll") for (int i = 0; i < 8; ++i) {                         \
            bf16x4 o;                                                           \
            _Pragma("unroll") for (int r = 0; r < 4; ++r)                       \
                o[r] = (short)f2bf_fast(ftanh_l2e(acc[i][j][r], bias2L));       \
            *(bf16x4*)&smem[col_l * 132 + i * 16 + quad * 4] = o;               \
        }                                                                       \
    }
    if (wave == 3) { EPI1(5) } else { EPI1(4) }
#undef EPI1
    __syncthreads();

    // ---- phase 2: spline math per (row, spline), unnormalized formulation ----
    for (int t = 0; t < 8; ++t) {
        const int row_l = t * 16 + r0;
        const int row = bm + row_l;
        const int cbase = sp * 17 * 132 + row_l;    // netS [col][row]

        float s[17];
#pragma unroll
        for (int c = 0; c < 17; c++)
            s[c] = bf2f((unsigned short)smem[cbase + c * 132]);

        // eh = 2^s (h part), e = 2^s (w part); |s|<1.45 so no max-subtraction
        float eh[9], e[8];
#pragma unroll
        for (int j = 0; j < 9; j++) eh[j] = EXP2F(s[j]);
#pragma unroll
        for (int c = 0; c < 8; c++) e[c]  = EXP2F(s[9 + c]);

        float cum_e[8], cum_u[8];
        cum_e[0] = e[0];
        cum_u[0] = e[0] * (eh[0] + eh[1]);
#pragma unroll
        for (int c = 1; c < 8; c++) {
            cum_e[c] = cum_e[c - 1] + e[c];
            cum_u[c] = fmaf(e[c], eh[c] + eh[c + 1], cum_u[c - 1]);
        }
        const float se = cum_e[7];
        const float su = cum_u[7];
        const float thr = xbv[t] * se;      // compare vs unnormalized knots

        float selE = e[0], selEH = eh[0], selEH1 = eh[1];
        float selCE = -EPSK * se, selCU = 0.f;
#pragma unroll
        for (int c = 1; c < 8; c++) {
            const bool tt = (cum_e[c - 1] < thr);
            selE   = tt ? e[c]         : selE;
            selEH  = tt ? eh[c]        : selEH;
            selEH1 = tt ? eh[c + 1]    : selEH1;
            selCE  = tt ? cum_e[c - 1] : selCE;
            selCU  = tt ? cum_u[c - 1] : selCU;
        }

        const float alpha = (thr - selCE) * RCPF(selE);
        const float dlt   = selEH1 - selEH;
        const float su_inv = RCPF(su);
        float p = fmaf(2.f * alpha, selE * selEH, selCU);
        p = fmaf(alpha * alpha, selE * dlt, p);
        out[(size_t)row * (2 * SDIM) + SDIM + sglob] = p * su_inv;

        const float g = fmaf(alpha, dlt, selEH) * (2.f * se * su_inv);
        float lg = LOG2F(g);
        lg += __shfl_xor(lg, 1);
        lg += __shfl_xor(lg, 2);
        lg += __shfl_xor(lg, 4);
        lg += __shfl_xor(lg, 8);
        if (sp == 0)
            atomicAdd(&out[(size_t)BROWS * (2 * SDIM) + row], -lg * LN2);
    }
}

// ---------------------------------------------------------------------------
extern "C" void kernel_launch(void* const* d_in, const int* in_sizes, int n_in,
                              void* d_out, int out_size, void* d_ws, size_t ws_size,
                              hipStream_t stream) {
    const float* x    = (const float*)d_in[0];
    const float* logd = (const float*)d_in[1];
    const float* W1   = (const float*)d_in[2];
    const float* b1   = (const float*)d_in[3];
    const float* W2   = (const float*)d_in[4];
    const float* b2   = (const float*)d_in[5];
    float* out = (float*)d_out;

    // ws layout (~17.9 MiB, unchanged)
    char* ws = (char*)d_ws;
    unsigned short* W1T = (unsigned short*)(ws + 32768);     // 512x512 bf16
    unsigned short* W2p = (unsigned short*)(ws + 557056);    // 8704x512 bf16 packed
    unsigned short* hid = (unsigned short*)(ws + 9469952);   // 8192x512 bf16

    prep_k<<<2720, 256, 0, stream>>>(W2, W2p, W1, W1T, logd, out, x);
    gemm1_mfma<<<dim3(4, 128), 256, 0, stream>>>(x, W1T, b1, hid);
    gemm2_spline_mfma<<<dim3(64, 32), 256, 0, stream>>>(hid, W2p, b2, x, out);
}